// Round 16
// baseline (205.742 us; speedup 1.0000x reference)
//
#include <hip/hip_runtime.h>
#include <cstddef>

typedef unsigned short u16;
typedef u16 u16x8 __attribute__((ext_vector_type(8)));
typedef __bf16 bf16x8 __attribute__((ext_vector_type(8)));
typedef float f32x4 __attribute__((ext_vector_type(4)));

static constexpr int V  = 2048;
static constexpr int DD = 64;   // D_IN == D_OUT

__device__ __forceinline__ u16 f2b(float f) {
  union { float f; unsigned int i; } x; x.f = f;
  return (u16)((x.i + 0x7fffu + ((x.i >> 16) & 1u)) >> 16);  // RNE
}

__device__ __forceinline__ void gll16(const void* g, void* l) {
  __builtin_amdgcn_global_load_lds(
      (const __attribute__((address_space(1))) void*)g,
      (__attribute__((address_space(3))) void*)l, 16, 0, 0);
}

// ---- K1: colsum[c] += per-block partial over 8 rows (fp32 atomics) ----
__global__ __launch_bounds__(256) void k_part(const float* __restrict__ adj,
                                              float* __restrict__ colsum) {
  int t = threadIdx.x;
  int r0 = blockIdx.x * 8;
  int c0 = t * 8;
  float acc[8] = {0.f, 0.f, 0.f, 0.f, 0.f, 0.f, 0.f, 0.f};
  for (int r = 0; r < 8; ++r) {
    const float4* p = (const float4*)(adj + (size_t)(r0 + r) * V + c0);
    float4 a0 = p[0], a1 = p[1];
    acc[0] += a0.x; acc[1] += a0.y; acc[2] += a0.z; acc[3] += a0.w;
    acc[4] += a1.x; acc[5] += a1.y; acc[6] += a1.z; acc[7] += a1.w;
  }
  #pragma unroll
  for (int k = 0; k < 8; ++k) atomicAdd(&colsum[c0 + k], acc[k]);
}

// ---- K2 fused: blocks 0..1023 = tn tiles; blocks 1024..2047 = proj tiles ----
__global__ __launch_bounds__(256) void k_prep(const float* __restrict__ adj,
                                              const float* __restrict__ colsum,
                                              const float* __restrict__ x,
                                              const float* __restrict__ w,
                                              u16* __restrict__ At,
                                              u16* __restrict__ Yt) {
  __shared__ float T[64][65];          // tn transpose tile (proj aliases as WT)
  __shared__ float rvv[64], rvj[64];   // tn: rinv for v-range / j-range
  int t = threadIdx.x;
  int bid = blockIdx.x;

  if (bid < 1024) {
    // ---------- tn: At[j][v] = adj[v][j] * rinv[v] * rinv[j] ----------
    int v0 = (bid & 31) * 64;
    int j0 = (bid >> 5) * 64;
    if (t < 128) {
      int col = (t < 64) ? (v0 + t) : (j0 + (t - 64));
      float rv = rsqrtf(colsum[col]);
      if (t < 64) rvv[t] = rv; else rvj[t - 64] = rv;
    }
    __syncthreads();
    #pragma unroll
    for (int it = 0; it < 2; ++it) {
      int f = t + it * 256;
      int row = f >> 3;          // v offset
      int cc = (f & 7) * 8;      // j chunk
      float rv = rvv[row];
      const float4* p = (const float4*)(adj + (size_t)(v0 + row) * V + j0 + cc);
      float4 a0 = p[0], a1 = p[1];
      T[row][cc + 0] = a0.x * rv; T[row][cc + 1] = a0.y * rv;
      T[row][cc + 2] = a0.z * rv; T[row][cc + 3] = a0.w * rv;
      T[row][cc + 4] = a1.x * rv; T[row][cc + 5] = a1.y * rv;
      T[row][cc + 6] = a1.z * rv; T[row][cc + 7] = a1.w * rv;
    }
    __syncthreads();
    #pragma unroll
    for (int it = 0; it < 2; ++it) {
      int f = t + it * 256;
      int jr = f >> 3;           // j offset
      int vc = (f & 7) * 8;      // v chunk
      float rj = rvj[jr];
      u16x8 o;
      #pragma unroll
      for (int k = 0; k < 8; ++k) o[k] = f2b(T[vc + k][jr] * rj);
      *(u16x8*)(At + (size_t)(j0 + jr) * V + v0 + vc) = o;
    }
  } else {
    // ---------- proj (MFMA): Yt[(ab*64+e)][v] = sum_d W[d][e]*x[ab,v,d] ----
    int pb = bid - 1024;
    int ab = pb >> 4;
    int v0 = (pb & 15) * 128;
    u16* WT = (u16*)&T[0][0];   // WT[e][d] bf16, stride 72 (9 KB, fits in T)

    {
      const float4* pw = (const float4*)(w + t * 16);
      float4 c0 = pw[0], c1 = pw[1], c2 = pw[2], c3 = pw[3];
      float vals[16] = {c0.x, c0.y, c0.z, c0.w, c1.x, c1.y, c1.z, c1.w,
                        c2.x, c2.y, c2.z, c2.w, c3.x, c3.y, c3.z, c3.w};
      #pragma unroll
      for (int k = 0; k < 16; ++k) {
        int idx = t * 16 + k;             // idx = d*64 + e
        WT[(idx & 63) * 72 + (idx >> 6)] = f2b(vals[k]);
      }
    }
    __syncthreads();

    int lane = t & 63, wave = t >> 6;
    int q = lane >> 4, r = lane & 15;
    int vbase = v0 + wave * 32;

    bf16x8 a[4][2];
    #pragma unroll
    for (int i = 0; i < 4; ++i)
      #pragma unroll
      for (int kk = 0; kk < 2; ++kk)
        a[i][kk] = __builtin_bit_cast(bf16x8,
            *(const u16x8*)(WT + (i * 16 + r) * 72 + kk * 32 + q * 8));

    const f32x4 vzero = {0.f, 0.f, 0.f, 0.f};
    f32x4 acc[4][2];
    #pragma unroll
    for (int i = 0; i < 4; ++i) { acc[i][0] = vzero; acc[i][1] = vzero; }

    #pragma unroll
    for (int nt = 0; nt < 2; ++nt) {
      int v = vbase + nt * 16 + r;
      const float* xp = x + ((size_t)ab * V + v) * DD;
      #pragma unroll
      for (int kk = 0; kk < 2; ++kk) {
        const float4* p = (const float4*)(xp + kk * 32 + q * 8);
        float4 b0 = p[0], b1 = p[1];
        u16x8 bu;
        bu[0] = f2b(b0.x); bu[1] = f2b(b0.y); bu[2] = f2b(b0.z); bu[3] = f2b(b0.w);
        bu[4] = f2b(b1.x); bu[5] = f2b(b1.y); bu[6] = f2b(b1.z); bu[7] = f2b(b1.w);
        bf16x8 bf = __builtin_bit_cast(bf16x8, bu);
        #pragma unroll
        for (int i = 0; i < 4; ++i)
          acc[i][nt] = __builtin_amdgcn_mfma_f32_16x16x32_bf16(a[i][kk], bf, acc[i][nt], 0, 0, 0);
      }
    }

    #pragma unroll
    for (int i = 0; i < 4; ++i)
      #pragma unroll
      for (int nt = 0; nt < 2; ++nt) {
        int v = vbase + nt * 16 + r;
        #pragma unroll
        for (int reg = 0; reg < 4; ++reg) {
          int e = i * 16 + q * 4 + reg;
          Yt[(size_t)(ab * 64 + e) * V + v] = f2b(acc[i][nt][reg]);
        }
      }
  }
}

// ---- K3: OUT[j,n] = sum_v At[j,v]*Yt[n,v]; +bias, relu; FP32 out ----
// R14 winner: 128x128 tile, BK=128 as 4 panels of 32, gll16 staging.
#define BM 128
#define BN 128
#define PANEL (128 * 32)

__global__ __launch_bounds__(256) void k_gemm(const u16* __restrict__ At,
                                              const u16* __restrict__ Yt,
                                              const float* __restrict__ bias,
                                              float* __restrict__ out) {
  __shared__ u16 Al[4 * PANEL];   // 32 KB
  __shared__ u16 Bl[4 * PANEL];   // 32 KB
  int t = threadIdx.x;
  int m0 = blockIdx.x * BM;
  int n0 = blockIdx.y * BN;
  int lane = t & 63;
  int wave = t >> 6;
  int wm = (wave & 1) * 64;
  int wn = (wave >> 1) * 64;
  int q = lane >> 4;
  int r = lane & 15;

  const f32x4 vzero = {0.f, 0.f, 0.f, 0.f};
  f32x4 acc[4][4];
  #pragma unroll
  for (int i = 0; i < 4; ++i)
    #pragma unroll
    for (int j = 0; j < 4; ++j) acc[i][j] = vzero;

  int eo0 = t * 8;
  int eo1 = (256 + t) * 8;
  int row0 = eo0 >> 5, col0 = eo0 & 31;
  int row1 = eo1 >> 5, col1 = eo1 & 31;

  for (int k0 = 0; k0 < V; k0 += 128) {
    __syncthreads();
    #pragma unroll
    for (int p = 0; p < 4; ++p) {
      int kp = k0 + p * 32;
      gll16(At + (size_t)(m0 + row0) * V + kp + col0, Al + p * PANEL + eo0);
      gll16(At + (size_t)(m0 + row1) * V + kp + col1, Al + p * PANEL + eo1);
      gll16(Yt + (size_t)(n0 + row0) * V + kp + col0, Bl + p * PANEL + eo0);
      gll16(Yt + (size_t)(n0 + row1) * V + kp + col1, Bl + p * PANEL + eo1);
    }
    __syncthreads();
    #pragma unroll
    for (int p = 0; p < 4; ++p) {
      bf16x8 a[4], b[4];
      #pragma unroll
      for (int i = 0; i < 4; ++i)
        a[i] = __builtin_bit_cast(bf16x8,
            *(const u16x8*)(Al + p * PANEL + (wm + i * 16 + r) * 32 + q * 8));
      #pragma unroll
      for (int j = 0; j < 4; ++j)
        b[j] = __builtin_bit_cast(bf16x8,
            *(const u16x8*)(Bl + p * PANEL + (wn + j * 16 + r) * 32 + q * 8));
      #pragma unroll
      for (int i = 0; i < 4; ++i)
        #pragma unroll
        for (int j = 0; j < 4; ++j)
          acc[i][j] = __builtin_amdgcn_mfma_f32_16x16x32_bf16(a[i], b[j], acc[i][j], 0, 0, 0);
    }
  }

  #pragma unroll
  for (int j = 0; j < 4; ++j) {
    int n = n0 + wn + j * 16 + r;
    int e = n & 63;
    int ab = n >> 6;
    float bv = bias[e];
    float* ob = out + (size_t)ab * (V * DD);
    #pragma unroll
    for (int i = 0; i < 4; ++i) {
      #pragma unroll
      for (int reg = 0; reg < 4; ++reg) {
        int jj = m0 + wm + i * 16 + q * 4 + reg;
        ob[(size_t)jj * DD + e] = fmaxf(acc[i][j][reg] + bv, 0.f);
      }
    }
  }
}

extern "C" void kernel_launch(void* const* d_in, const int* in_sizes, int n_in,
                              void* d_out, int out_size, void* d_ws, size_t ws_size,
                              hipStream_t stream) {
  const float* adj  = (const float*)d_in[0];
  const float* x    = (const float*)d_in[1];
  const float* w    = (const float*)d_in[2];
  const float* bias = (const float*)d_in[3];
  float* out = (float*)d_out;

  // Workspace (24 MB + 8 KB):
  //   At     @ 0     : 2048*2048 bf16 = 8 MB   (live k_prep..k_gemm)
  //   Yt     @ 8 MB  : 4096*2048 bf16 = 16 MB  (live k_prep..k_gemm)
  //   colsum @ 24 MB : 2048 f32 = 8 KB         (live k_part..k_prep)
  char* ws = (char*)d_ws;
  u16*   At     = (u16*)ws;
  u16*   Yt     = (u16*)(ws + ((size_t)8 << 20));
  float* colsum = (float*)(ws + ((size_t)24 << 20));

  (void)hipMemsetAsync(colsum, 0, V * sizeof(float), stream);
  k_part<<<256, 256, 0, stream>>>(adj, colsum);
  k_prep<<<2048, 256, 0, stream>>>(adj, colsum, x, w, At, Yt);
  k_gemm<<<dim3(16, 32), 256, 0, stream>>>(At, Yt, bias, out);
}

// Round 17
// 148.130 us; speedup vs baseline: 1.3889x; 1.3889x over previous
//
#include <hip/hip_runtime.h>
#include <cstddef>

typedef unsigned short u16;
typedef u16 u16x8 __attribute__((ext_vector_type(8)));
typedef __bf16 bf16x8 __attribute__((ext_vector_type(8)));
typedef float f32x4 __attribute__((ext_vector_type(4)));

static constexpr int V  = 2048;
static constexpr int DD = 64;   // D_IN == D_OUT

__device__ __forceinline__ u16 f2b(float f) {
  union { float f; unsigned int i; } x; x.f = f;
  return (u16)((x.i + 0x7fffu + ((x.i >> 16) & 1u)) >> 16);  // RNE
}

__device__ __forceinline__ void gll16(const void* g, void* l) {
  __builtin_amdgcn_global_load_lds(
      (const __attribute__((address_space(1))) void*)g,
      (__attribute__((address_space(3))) void*)l, 16, 0, 0);
}

// ---- K1: partial column sums of adj: partial[b][c] = sum of 32 rows ----
// NOTE: two-phase reduction, NOT atomics — R16 measured 256-way atomic
// contention on 2048 addresses at ~68 µs vs ~8 µs for this form.
__global__ __launch_bounds__(256) void k_part(const float* __restrict__ adj,
                                              float* __restrict__ partial) {
  int t = threadIdx.x;
  int r0 = blockIdx.x * 32;
  int c0 = t * 8;
  float acc[8] = {0.f, 0.f, 0.f, 0.f, 0.f, 0.f, 0.f, 0.f};
  for (int r = 0; r < 32; ++r) {
    const float4* p = (const float4*)(adj + (size_t)(r0 + r) * V + c0);
    float4 a0 = p[0], a1 = p[1];
    acc[0] += a0.x; acc[1] += a0.y; acc[2] += a0.z; acc[3] += a0.w;
    acc[4] += a1.x; acc[5] += a1.y; acc[6] += a1.z; acc[7] += a1.w;
  }
  #pragma unroll
  for (int k = 0; k < 8; ++k) partial[(size_t)blockIdx.x * V + c0 + k] = acc[k];
}

// ---- K2 fused: blocks 0..1023 = tn tiles; blocks 1024..2047 = proj tiles ----
__global__ __launch_bounds__(256) void k_prep(const float* __restrict__ adj,
                                              const float* __restrict__ partial,
                                              const float* __restrict__ x,
                                              const float* __restrict__ w,
                                              u16* __restrict__ At,
                                              u16* __restrict__ Yt) {
  __shared__ float T[64][65];          // tn transpose tile (proj aliases as WT)
  __shared__ float rvv[64], rvj[64];   // tn: rinv for v-range / j-range
  int t = threadIdx.x;
  int bid = blockIdx.x;

  if (bid < 1024) {
    // ---------- tn: At[j][v] = adj[v][j] * rinv[v] * rinv[j] ----------
    int v0 = (bid & 31) * 64;
    int j0 = (bid >> 5) * 64;
    if (t < 128) {
      int col = (t < 64) ? (v0 + t) : (j0 + (t - 64));
      float s = 0.f;
      for (int i = 0; i < 64; ++i) s += partial[(size_t)i * V + col];
      float rv = rsqrtf(s);
      if (t < 64) rvv[t] = rv; else rvj[t - 64] = rv;
    }
    __syncthreads();
    #pragma unroll
    for (int it = 0; it < 2; ++it) {
      int f = t + it * 256;
      int row = f >> 3;          // v offset
      int cc = (f & 7) * 8;      // j chunk
      float rv = rvv[row];
      const float4* p = (const float4*)(adj + (size_t)(v0 + row) * V + j0 + cc);
      float4 a0 = p[0], a1 = p[1];
      T[row][cc + 0] = a0.x * rv; T[row][cc + 1] = a0.y * rv;
      T[row][cc + 2] = a0.z * rv; T[row][cc + 3] = a0.w * rv;
      T[row][cc + 4] = a1.x * rv; T[row][cc + 5] = a1.y * rv;
      T[row][cc + 6] = a1.z * rv; T[row][cc + 7] = a1.w * rv;
    }
    __syncthreads();
    #pragma unroll
    for (int it = 0; it < 2; ++it) {
      int f = t + it * 256;
      int jr = f >> 3;           // j offset
      int vc = (f & 7) * 8;      // v chunk
      float rj = rvj[jr];
      u16x8 o;
      #pragma unroll
      for (int k = 0; k < 8; ++k) o[k] = f2b(T[vc + k][jr] * rj);
      *(u16x8*)(At + (size_t)(j0 + jr) * V + v0 + vc) = o;
    }
  } else {
    // ---------- proj (MFMA): Yt[(ab*64+e)][v] = sum_d W[d][e]*x[ab,v,d] ----
    int pb = bid - 1024;
    int ab = pb >> 4;
    int v0 = (pb & 15) * 128;
    u16* WT = (u16*)&T[0][0];   // WT[e][d] bf16, stride 72 (9 KB, fits in T)

    {
      const float4* pw = (const float4*)(w + t * 16);
      float4 c0 = pw[0], c1 = pw[1], c2 = pw[2], c3 = pw[3];
      float vals[16] = {c0.x, c0.y, c0.z, c0.w, c1.x, c1.y, c1.z, c1.w,
                        c2.x, c2.y, c2.z, c2.w, c3.x, c3.y, c3.z, c3.w};
      #pragma unroll
      for (int k = 0; k < 16; ++k) {
        int idx = t * 16 + k;             // idx = d*64 + e
        WT[(idx & 63) * 72 + (idx >> 6)] = f2b(vals[k]);
      }
    }
    __syncthreads();

    int lane = t & 63, wave = t >> 6;
    int q = lane >> 4, r = lane & 15;
    int vbase = v0 + wave * 32;

    bf16x8 a[4][2];
    #pragma unroll
    for (int i = 0; i < 4; ++i)
      #pragma unroll
      for (int kk = 0; kk < 2; ++kk)
        a[i][kk] = __builtin_bit_cast(bf16x8,
            *(const u16x8*)(WT + (i * 16 + r) * 72 + kk * 32 + q * 8));

    const f32x4 vzero = {0.f, 0.f, 0.f, 0.f};
    f32x4 acc[4][2];
    #pragma unroll
    for (int i = 0; i < 4; ++i) { acc[i][0] = vzero; acc[i][1] = vzero; }

    #pragma unroll
    for (int nt = 0; nt < 2; ++nt) {
      int v = vbase + nt * 16 + r;
      const float* xp = x + ((size_t)ab * V + v) * DD;
      #pragma unroll
      for (int kk = 0; kk < 2; ++kk) {
        const float4* p = (const float4*)(xp + kk * 32 + q * 8);
        float4 b0 = p[0], b1 = p[1];
        u16x8 bu;
        bu[0] = f2b(b0.x); bu[1] = f2b(b0.y); bu[2] = f2b(b0.z); bu[3] = f2b(b0.w);
        bu[4] = f2b(b1.x); bu[5] = f2b(b1.y); bu[6] = f2b(b1.z); bu[7] = f2b(b1.w);
        bf16x8 bf = __builtin_bit_cast(bf16x8, bu);
        #pragma unroll
        for (int i = 0; i < 4; ++i)
          acc[i][nt] = __builtin_amdgcn_mfma_f32_16x16x32_bf16(a[i][kk], bf, acc[i][nt], 0, 0, 0);
      }
    }

    #pragma unroll
    for (int i = 0; i < 4; ++i)
      #pragma unroll
      for (int nt = 0; nt < 2; ++nt) {
        int v = vbase + nt * 16 + r;
        #pragma unroll
        for (int reg = 0; reg < 4; ++reg) {
          int e = i * 16 + q * 4 + reg;
          Yt[(size_t)(ab * 64 + e) * V + v] = f2b(acc[i][nt][reg]);
        }
      }
  }
}

// ---- K3: OUT[j,n] = sum_v At[j,v]*Yt[n,v]; +bias, relu; FP32 out ----
// Measured optimum: 128x128 tile, BK=128 as 4 panels of 32, gll16 staging.
// (BN=64 regressed: 45->67 µs, R15. BK=32 was 52 µs, R12.)
#define BM 128
#define BN 128
#define PANEL (128 * 32)

__global__ __launch_bounds__(256) void k_gemm(const u16* __restrict__ At,
                                              const u16* __restrict__ Yt,
                                              const float* __restrict__ bias,
                                              float* __restrict__ out) {
  __shared__ u16 Al[4 * PANEL];   // 32 KB
  __shared__ u16 Bl[4 * PANEL];   // 32 KB
  int t = threadIdx.x;
  int m0 = blockIdx.x * BM;
  int n0 = blockIdx.y * BN;
  int lane = t & 63;
  int wave = t >> 6;
  int wm = (wave & 1) * 64;
  int wn = (wave >> 1) * 64;
  int q = lane >> 4;
  int r = lane & 15;

  const f32x4 vzero = {0.f, 0.f, 0.f, 0.f};
  f32x4 acc[4][4];
  #pragma unroll
  for (int i = 0; i < 4; ++i)
    #pragma unroll
    for (int j = 0; j < 4; ++j) acc[i][j] = vzero;

  int eo0 = t * 8;
  int eo1 = (256 + t) * 8;
  int row0 = eo0 >> 5, col0 = eo0 & 31;
  int row1 = eo1 >> 5, col1 = eo1 & 31;

  for (int k0 = 0; k0 < V; k0 += 128) {
    __syncthreads();
    #pragma unroll
    for (int p = 0; p < 4; ++p) {
      int kp = k0 + p * 32;
      gll16(At + (size_t)(m0 + row0) * V + kp + col0, Al + p * PANEL + eo0);
      gll16(At + (size_t)(m0 + row1) * V + kp + col1, Al + p * PANEL + eo1);
      gll16(Yt + (size_t)(n0 + row0) * V + kp + col0, Bl + p * PANEL + eo0);
      gll16(Yt + (size_t)(n0 + row1) * V + kp + col1, Bl + p * PANEL + eo1);
    }
    __syncthreads();
    #pragma unroll
    for (int p = 0; p < 4; ++p) {
      bf16x8 a[4], b[4];
      #pragma unroll
      for (int i = 0; i < 4; ++i)
        a[i] = __builtin_bit_cast(bf16x8,
            *(const u16x8*)(Al + p * PANEL + (wm + i * 16 + r) * 32 + q * 8));
      #pragma unroll
      for (int j = 0; j < 4; ++j)
        b[j] = __builtin_bit_cast(bf16x8,
            *(const u16x8*)(Bl + p * PANEL + (wn + j * 16 + r) * 32 + q * 8));
      #pragma unroll
      for (int i = 0; i < 4; ++i)
        #pragma unroll
        for (int j = 0; j < 4; ++j)
          acc[i][j] = __builtin_amdgcn_mfma_f32_16x16x32_bf16(a[i], b[j], acc[i][j], 0, 0, 0);
    }
  }

  #pragma unroll
  for (int j = 0; j < 4; ++j) {
    int n = n0 + wn + j * 16 + r;
    int e = n & 63;
    int ab = n >> 6;
    float bv = bias[e];
    float* ob = out + (size_t)ab * (V * DD);
    #pragma unroll
    for (int i = 0; i < 4; ++i) {
      #pragma unroll
      for (int reg = 0; reg < 4; ++reg) {
        int jj = m0 + wm + i * 16 + q * 4 + reg;
        ob[(size_t)jj * DD + e] = fmaxf(acc[i][j][reg] + bv, 0.f);
      }
    }
  }
}

extern "C" void kernel_launch(void* const* d_in, const int* in_sizes, int n_in,
                              void* d_out, int out_size, void* d_ws, size_t ws_size,
                              hipStream_t stream) {
  const float* adj  = (const float*)d_in[0];
  const float* x    = (const float*)d_in[1];
  const float* w    = (const float*)d_in[2];
  const float* bias = (const float*)d_in[3];
  float* out = (float*)d_out;

  // Workspace (24.5 MB):
  //   At      @ 0     : 2048*2048 bf16 = 8 MB   (live k_prep..k_gemm)
  //   Yt      @ 8 MB  : 4096*2048 bf16 = 16 MB  (live k_prep..k_gemm)
  //   partial @ 24 MB : 64*2048 f32 = 512 KB    (live k_part..k_prep)
  char* ws = (char*)d_ws;
  u16*   At      = (u16*)ws;
  u16*   Yt      = (u16*)(ws + ((size_t)8 << 20));
  float* partial = (float*)(ws + ((size_t)24 << 20));

  k_part<<<64, 256, 0, stream>>>(adj, partial);
  k_prep<<<2048, 256, 0, stream>>>(adj, partial, x, w, At, Yt);
  k_gemm<<<dim3(16, 32), 256, 0, stream>>>(At, Yt, bias, out);
}